// Round 14
// baseline (399.343 us; speedup 1.0000x reference)
//
#include <hip/hip_runtime.h>
#include <hip/hip_cooperative_groups.h>

namespace cg = cooperative_groups;

#define D 128
#define SCAN_BLK 256

typedef short  bf16x8 __attribute__((ext_vector_type(8)));
typedef float  f32x4  __attribute__((ext_vector_type(4)));

// round-to-nearest-even float -> bf16 bits
static __device__ __forceinline__ unsigned short f2bf(float f) {
    unsigned u = __float_as_uint(f);
    u += 0x7FFFu + ((u >> 16) & 1u);
    return (unsigned short)(u >> 16);
}
static __device__ __forceinline__ float bf2f_lo(unsigned u) {
    return __uint_as_float((u & 0xFFFFu) << 16);
}
static __device__ __forceinline__ float bf2f_hi(unsigned u) {
    return __uint_as_float(u & 0xFFFF0000u);
}

// =================================================================
// Cooperative mega-kernel: all phases of the R11 pipeline in one
// dispatch, grid.sync() between phases (saves ~15 us of dispatch gaps).
// Phase bodies are the R8/R11-proven ones.
// =================================================================
__global__ __launch_bounds__(256) void mega(
    const int* __restrict__ rows, const int* __restrict__ cols,
    const float* __restrict__ vals, const float* __restrict__ W,
    const float* __restrict__ b, const float* __restrict__ x,
    int* __restrict__ counts, int* __restrict__ offs, int* __restrict__ cursor,
    int* __restrict__ bsums, int2* __restrict__ evec,
    unsigned short* __restrict__ Wb, unsigned short* __restrict__ hb,
    float* __restrict__ out,
    int n_nodes, int n_edges, int nScanChunks, int gemmTiles, int gemmShare) {
    cg::grid_group grid = cg::this_grid();
    const int t   = threadIdx.x;
    const int bid = blockIdx.x;
    const int G   = gridDim.x;
    const int gstride = G * 256;
    __shared__ int sh[SCAN_BLK];

    // ---- P0: zero counts + convert W to bf16
    for (int i = bid * 256 + t; i < n_nodes; i += gstride) counts[i] = 0;
    for (int i = bid * 256 + t; i < D * D;   i += gstride) Wb[i] = f2bf(W[i]);
    grid.sync();

    // ---- P1: histogram of destination rows
    for (int i = bid * 256 + t; i < n_edges; i += gstride)
        atomicAdd(&counts[rows[i]], 1);
    grid.sync();

    // ---- P2a: per-chunk exclusive scans (chunk = 256 counts)
    for (int ch = bid; ch < nScanChunks; ch += G) {
        int i = ch * 256 + t;
        int v = (i < n_nodes) ? counts[i] : 0;
        sh[t] = v;
        __syncthreads();
        for (int off = 1; off < 256; off <<= 1) {
            int add = (t >= off) ? sh[t - off] : 0;
            __syncthreads();
            sh[t] += add;
            __syncthreads();
        }
        if (i < n_nodes) offs[i] = sh[t] - v;
        if (t == 255) bsums[ch] = sh[255];
        __syncthreads();
    }
    grid.sync();

    // ---- P2b: scan chunk sums (nScanChunks <= 256) by block 0
    if (bid == 0) {
        int v = (t < nScanChunks) ? bsums[t] : 0;
        sh[t] = v;
        __syncthreads();
        for (int off = 1; off < 256; off <<= 1) {
            int add = (t >= off) ? sh[t - off] : 0;
            __syncthreads();
            sh[t] += add;
            __syncthreads();
        }
        if (t < nScanChunks) bsums[t] = sh[t] - v;
        if (t == 255) offs[n_nodes] = sh[255];
    }
    grid.sync();

    // ---- P2c: add chunk offsets -> offs, cursor
    for (int ch = bid; ch < nScanChunks; ch += G) {
        int i = ch * 256 + t;
        if (i < n_nodes) {
            int o = offs[i] + bsums[ch];
            offs[i]   = o;
            cursor[i] = o;
        }
    }
    grid.sync();

    // ---- P3: gemm (blocks [0,gemmShare)) || permute (the rest), co-resident
    if (bid < gemmShare) {
        const int lane = t & 63;
        const int wv   = t >> 6;
        const int m    = lane & 15;
        const int kg   = lane >> 4;
        for (int gb = bid; gb < gemmTiles; gb += gemmShare) {
            const int row0 = gb * 64 + wv * 16;
            if (row0 >= n_nodes) continue;
            int arow = row0 + m;
            if (arow >= n_nodes) arow = n_nodes - 1;
            const float* xr = x + (size_t)arow * D + kg * 8;

            f32x4 acc[8];
#pragma unroll
            for (int n = 0; n < 8; ++n) acc[n] = (f32x4){0.f, 0.f, 0.f, 0.f};
#pragma unroll
            for (int ks = 0; ks < 4; ++ks) {
                float4 f0 = *(const float4*)(xr + ks * 32);
                float4 f1 = *(const float4*)(xr + ks * 32 + 4);
                bf16x8 a;
                a[0] = (short)f2bf(f0.x); a[1] = (short)f2bf(f0.y);
                a[2] = (short)f2bf(f0.z); a[3] = (short)f2bf(f0.w);
                a[4] = (short)f2bf(f1.x); a[5] = (short)f2bf(f1.y);
                a[6] = (short)f2bf(f1.z); a[7] = (short)f2bf(f1.w);
#pragma unroll
                for (int n = 0; n < 8; ++n) {
                    bf16x8 bf = *(const bf16x8*)&Wb[(size_t)(n * 16 + m) * D + ks * 32 + kg * 8];
                    acc[n] = __builtin_amdgcn_mfma_f32_16x16x32_bf16(a, bf, acc[n], 0, 0, 0);
                }
            }
#pragma unroll
            for (int n = 0; n < 8; ++n) {
                int col = n * 16 + m;
                float bc = b[col];
#pragma unroll
                for (int j = 0; j < 4; ++j) {
                    int rr = row0 + kg * 4 + j;
                    if (rr < n_nodes) hb[(size_t)rr * D + col] = f2bf(acc[n][j] + bc);
                }
            }
        }
    } else {
        const int slot  = bid - gemmShare;
        const int nperm = G - gemmShare;
        for (int i = slot * 256 + t; i < n_edges; i += nperm * 256) {
            int rr  = rows[i];
            int pos = atomicAdd(&cursor[rr], 1);
            evec[pos] = make_int2(cols[i], __float_as_int(vals[i]));
        }
    }
    grid.sync();

    // ---- P4: aggregate — one wave per node, lane owns 2 cols,
    // uniform masked 8-deep rounds (R12 body, equal-best measured).
    {
        const int lane = t & 63;
        const int wv   = t >> 6;
        const int c0   = lane * 2;
        for (int wid = bid * 4 + wv; wid < n_nodes; wid += G * 4) {
            const int s = offs[wid];
            const int e = offs[wid + 1];
            const int rounds = (e - s + 7) >> 3;
            float2 acc = make_float2(0.f, 0.f);
            for (int rd = 0; rd < rounds; ++rd) {
                const int k   = s + rd * 8;
                const int em1 = e - 1;
                int2 r0 = evec[min(k + 0, em1)];
                int2 r1 = evec[min(k + 1, em1)];
                int2 r2 = evec[min(k + 2, em1)];
                int2 r3 = evec[min(k + 3, em1)];
                int2 r4 = evec[min(k + 4, em1)];
                int2 r5 = evec[min(k + 5, em1)];
                int2 r6 = evec[min(k + 6, em1)];
                int2 r7 = evec[min(k + 7, em1)];
                unsigned u0 = *(const unsigned*)&hb[(size_t)r0.x * D + c0];
                unsigned u1 = *(const unsigned*)&hb[(size_t)r1.x * D + c0];
                unsigned u2 = *(const unsigned*)&hb[(size_t)r2.x * D + c0];
                unsigned u3 = *(const unsigned*)&hb[(size_t)r3.x * D + c0];
                unsigned u4 = *(const unsigned*)&hb[(size_t)r4.x * D + c0];
                unsigned u5 = *(const unsigned*)&hb[(size_t)r5.x * D + c0];
                unsigned u6 = *(const unsigned*)&hb[(size_t)r6.x * D + c0];
                unsigned u7 = *(const unsigned*)&hb[(size_t)r7.x * D + c0];
                float v0 = (k + 0 < e) ? __int_as_float(r0.y) : 0.f;
                float v1 = (k + 1 < e) ? __int_as_float(r1.y) : 0.f;
                float v2 = (k + 2 < e) ? __int_as_float(r2.y) : 0.f;
                float v3 = (k + 3 < e) ? __int_as_float(r3.y) : 0.f;
                float v4 = (k + 4 < e) ? __int_as_float(r4.y) : 0.f;
                float v5 = (k + 5 < e) ? __int_as_float(r5.y) : 0.f;
                float v6 = (k + 6 < e) ? __int_as_float(r6.y) : 0.f;
                float v7 = (k + 7 < e) ? __int_as_float(r7.y) : 0.f;
                acc.x += v0 * bf2f_lo(u0); acc.y += v0 * bf2f_hi(u0);
                acc.x += v1 * bf2f_lo(u1); acc.y += v1 * bf2f_hi(u1);
                acc.x += v2 * bf2f_lo(u2); acc.y += v2 * bf2f_hi(u2);
                acc.x += v3 * bf2f_lo(u3); acc.y += v3 * bf2f_hi(u3);
                acc.x += v4 * bf2f_lo(u4); acc.y += v4 * bf2f_hi(u4);
                acc.x += v5 * bf2f_lo(u5); acc.y += v5 * bf2f_hi(u5);
                acc.x += v6 * bf2f_lo(u6); acc.y += v6 * bf2f_hi(u6);
                acc.x += v7 * bf2f_lo(u7); acc.y += v7 * bf2f_hi(u7);
            }
            *(float2*)&out[(size_t)wid * D + c0] = acc;
        }
    }
}

// =================================================================
// Fallback path: the R11 proven kernel sequence (used if the
// cooperative launch is rejected). Identical math -> identical output.
// =================================================================
__global__ __launch_bounds__(256) void fused_pre(
    const int* __restrict__ rows, int* __restrict__ counts, int n_edges,
    const float* __restrict__ W, unsigned short* __restrict__ Wb, int histBlocks) {
    int bid = blockIdx.x;
    if (bid < histBlocks) {
        int i = bid * 256 + threadIdx.x;
        if (i < n_edges) atomicAdd(&counts[rows[i]], 1);
    } else {
        int i = (bid - histBlocks) * 256 + threadIdx.x;
        if (i < D * D) Wb[i] = f2bf(W[i]);
    }
}

__global__ __launch_bounds__(256) void fused_main(
    const int* __restrict__ rows, const int* __restrict__ cols,
    const float* __restrict__ vals, int* __restrict__ cursor,
    int2* __restrict__ evec, int n_edges, int permSlots,
    const float* __restrict__ x, const unsigned short* __restrict__ Wb,
    const float* __restrict__ b, unsigned short* __restrict__ hb, int n_rows) {
    const int bid = blockIdx.x;
    const int g   = bid / 5;
    const int r5  = bid % 5;

    if (r5 >= 2) {
        const int slot   = g * 3 + (r5 - 2);
        const int stride = permSlots * 256;
        for (int i = slot * 256 + threadIdx.x; i < n_edges; i += stride) {
            int rr  = rows[i];
            int pos = atomicAdd(&cursor[rr], 1);
            evec[pos] = make_int2(cols[i], __float_as_int(vals[i]));
        }
        return;
    }

    const int gb   = g * 2 + r5;
    const int lane = threadIdx.x & 63;
    const int wv   = threadIdx.x >> 6;
    const int row0 = gb * 64 + wv * 16;
    if (row0 >= n_rows) return;
    const int m  = lane & 15;
    const int kg = lane >> 4;

    int arow = row0 + m;
    if (arow >= n_rows) arow = n_rows - 1;
    const float* xr = x + (size_t)arow * D + kg * 8;

    f32x4 acc[8];
#pragma unroll
    for (int n = 0; n < 8; ++n) acc[n] = (f32x4){0.f, 0.f, 0.f, 0.f};
#pragma unroll
    for (int ks = 0; ks < 4; ++ks) {
        float4 f0 = *(const float4*)(xr + ks * 32);
        float4 f1 = *(const float4*)(xr + ks * 32 + 4);
        bf16x8 a;
        a[0] = (short)f2bf(f0.x); a[1] = (short)f2bf(f0.y);
        a[2] = (short)f2bf(f0.z); a[3] = (short)f2bf(f0.w);
        a[4] = (short)f2bf(f1.x); a[5] = (short)f2bf(f1.y);
        a[6] = (short)f2bf(f1.z); a[7] = (short)f2bf(f1.w);
#pragma unroll
        for (int n = 0; n < 8; ++n) {
            bf16x8 bf = *(const bf16x8*)&Wb[(size_t)(n * 16 + m) * D + ks * 32 + kg * 8];
            acc[n] = __builtin_amdgcn_mfma_f32_16x16x32_bf16(a, bf, acc[n], 0, 0, 0);
        }
    }
#pragma unroll
    for (int n = 0; n < 8; ++n) {
        int col = n * 16 + m;
        float bc = b[col];
#pragma unroll
        for (int j = 0; j < 4; ++j) {
            int rr = row0 + kg * 4 + j;
            if (rr < n_rows) hb[(size_t)rr * D + col] = f2bf(acc[n][j] + bc);
        }
    }
}

__global__ __launch_bounds__(SCAN_BLK) void scan_local(
    const int* __restrict__ counts, int* __restrict__ offs,
    int* __restrict__ blockSums, int n) {
    __shared__ int sh[SCAN_BLK];
    const int t = threadIdx.x;
    const int i = blockIdx.x * SCAN_BLK + t;
    int v = (i < n) ? counts[i] : 0;
    sh[t] = v;
    __syncthreads();
    for (int off = 1; off < SCAN_BLK; off <<= 1) {
        int add = (t >= off) ? sh[t - off] : 0;
        __syncthreads();
        sh[t] += add;
        __syncthreads();
    }
    if (i < n) offs[i] = sh[t] - v;
    if (t == SCAN_BLK - 1) blockSums[blockIdx.x] = sh[SCAN_BLK - 1];
}

__global__ __launch_bounds__(1024) void scan_blocks(
    int* __restrict__ blockSums, int* __restrict__ total, int nb) {
    __shared__ int sh[1024];
    const int t = threadIdx.x;
    int v = (t < nb) ? blockSums[t] : 0;
    sh[t] = v;
    __syncthreads();
    for (int off = 1; off < 1024; off <<= 1) {
        int add = (t >= off) ? sh[t - off] : 0;
        __syncthreads();
        sh[t] += add;
        __syncthreads();
    }
    if (t < nb) blockSums[t] = sh[t] - v;
    if (t == 1023) *total = sh[1023];
}

__global__ __launch_bounds__(SCAN_BLK) void scan_add(
    int* __restrict__ offs, int* __restrict__ cursor,
    const int* __restrict__ blockSums, int n) {
    const int i = blockIdx.x * SCAN_BLK + threadIdx.x;
    if (i < n) {
        int o = offs[i] + blockSums[blockIdx.x];
        offs[i]   = o;
        cursor[i] = o;
    }
}

__global__ __launch_bounds__(256, 4) void aggregate(
    const int* __restrict__ offs, const int2* __restrict__ evec,
    const unsigned short* __restrict__ hb, float* __restrict__ out, int n_nodes) {
    const int lane = threadIdx.x & 63;
    const int wv   = threadIdx.x >> 6;
    const int c0   = lane * 2;
    int wid = blockIdx.x * 4 + wv;
    if (wid >= n_nodes) return;

    const int s = offs[wid];
    const int e = offs[wid + 1];
    const int rounds = (e - s + 7) >> 3;
    float2 acc = make_float2(0.f, 0.f);
    for (int rd = 0; rd < rounds; ++rd) {
        const int k   = s + rd * 8;
        const int em1 = e - 1;
        int2 r0 = evec[min(k + 0, em1)];
        int2 r1 = evec[min(k + 1, em1)];
        int2 r2 = evec[min(k + 2, em1)];
        int2 r3 = evec[min(k + 3, em1)];
        int2 r4 = evec[min(k + 4, em1)];
        int2 r5 = evec[min(k + 5, em1)];
        int2 r6 = evec[min(k + 6, em1)];
        int2 r7 = evec[min(k + 7, em1)];
        unsigned u0 = *(const unsigned*)&hb[(size_t)r0.x * D + c0];
        unsigned u1 = *(const unsigned*)&hb[(size_t)r1.x * D + c0];
        unsigned u2 = *(const unsigned*)&hb[(size_t)r2.x * D + c0];
        unsigned u3 = *(const unsigned*)&hb[(size_t)r3.x * D + c0];
        unsigned u4 = *(const unsigned*)&hb[(size_t)r4.x * D + c0];
        unsigned u5 = *(const unsigned*)&hb[(size_t)r5.x * D + c0];
        unsigned u6 = *(const unsigned*)&hb[(size_t)r6.x * D + c0];
        unsigned u7 = *(const unsigned*)&hb[(size_t)r7.x * D + c0];
        float v0 = (k + 0 < e) ? __int_as_float(r0.y) : 0.f;
        float v1 = (k + 1 < e) ? __int_as_float(r1.y) : 0.f;
        float v2 = (k + 2 < e) ? __int_as_float(r2.y) : 0.f;
        float v3 = (k + 3 < e) ? __int_as_float(r3.y) : 0.f;
        float v4 = (k + 4 < e) ? __int_as_float(r4.y) : 0.f;
        float v5 = (k + 5 < e) ? __int_as_float(r5.y) : 0.f;
        float v6 = (k + 6 < e) ? __int_as_float(r6.y) : 0.f;
        float v7 = (k + 7 < e) ? __int_as_float(r7.y) : 0.f;
        acc.x += v0 * bf2f_lo(u0); acc.y += v0 * bf2f_hi(u0);
        acc.x += v1 * bf2f_lo(u1); acc.y += v1 * bf2f_hi(u1);
        acc.x += v2 * bf2f_lo(u2); acc.y += v2 * bf2f_hi(u2);
        acc.x += v3 * bf2f_lo(u3); acc.y += v3 * bf2f_hi(u3);
        acc.x += v4 * bf2f_lo(u4); acc.y += v4 * bf2f_hi(u4);
        acc.x += v5 * bf2f_lo(u5); acc.y += v5 * bf2f_hi(u5);
        acc.x += v6 * bf2f_lo(u6); acc.y += v6 * bf2f_hi(u6);
        acc.x += v7 * bf2f_lo(u7); acc.y += v7 * bf2f_hi(u7);
    }
    *(float2*)&out[(size_t)wid * D + c0] = acc;
}

// ---------------------------------------------------------------- launch
static inline size_t align16(size_t x) { return (x + 15) & ~(size_t)15; }

extern "C" void kernel_launch(void* const* d_in, const int* in_sizes, int n_in,
                              void* d_out, int out_size, void* d_ws, size_t ws_size,
                              hipStream_t stream) {
    const float* x    = (const float*)d_in[0];
    const int*   rows = (const int*)  d_in[1];
    const int*   cols = (const int*)  d_in[2];
    const float* vals = (const float*)d_in[3];
    const float* W    = (const float*)d_in[4];
    const float* b    = (const float*)d_in[5];
    float*       out  = (float*)d_out;

    int n_nodes = in_sizes[0] / D;   // 50000
    int n_edges = in_sizes[1];       // 800000
    const int nScanChunks = (n_nodes + 255) / 256;         // 196 (must be <= 256)
    int gemmTiles = (n_nodes + 63) / 64;                   // 782

    // ---- workspace layout (16B-aligned regions)
    char*  base    = (char*)d_ws;
    size_t off     = 0;
    unsigned short* Wb = (unsigned short*)(base + off); off = align16(off + (size_t)D * D * 2);
    unsigned short* hb = (unsigned short*)(base + off); off = align16(off + (size_t)n_nodes * D * 2);
    int*   counts  = (int*)  (base + off); off = align16(off + (size_t)n_nodes * 4);
    int*   offs    = (int*)  (base + off); off = align16(off + ((size_t)n_nodes + 1) * 4);
    int*   cursor  = (int*)  (base + off); off = align16(off + (size_t)n_nodes * 4);
    int*   bsums   = (int*)  (base + off); off = align16(off + (size_t)1024 * 4);
    int2*  evec    = (int2*) (base + off); off = align16(off + (size_t)n_edges * 8);
    (void)ws_size;

    // ---- preferred: single cooperative mega-kernel
    bool launched = false;
    if (nScanChunks <= 256) {
        int maxB = 0;
        hipError_t occ = hipOccupancyMaxActiveBlocksPerMultiprocessor(
            &maxB, (const void*)mega, 256, 0);
        if (occ != hipSuccess || maxB < 1) maxB = 4;
        int G = maxB * 256;              // 256 CUs on MI355X
        if (G > 2048) G = 2048;
        int gemmShare = (G * 2) / 5;
        if (gemmShare < 1) gemmShare = 1;
        if (gemmShare >= G) gemmShare = G - 1;

        void* args[] = {
            (void*)&rows, (void*)&cols, (void*)&vals, (void*)&W, (void*)&b,
            (void*)&x, (void*)&counts, (void*)&offs, (void*)&cursor,
            (void*)&bsums, (void*)&evec, (void*)&Wb, (void*)&hb, (void*)&out,
            (void*)&n_nodes, (void*)&n_edges, (void*)&nScanChunks,
            (void*)&gemmTiles, (void*)&gemmShare
        };
        hipError_t err = hipLaunchCooperativeKernel(
            (const void*)mega, dim3(G), dim3(256), args, 0, stream);
        launched = (err == hipSuccess);
    }

    // ---- fallback: R11 proven sequence
    if (!launched) {
        const int histBlocks = (n_edges + 255) / 256;
        const int convBlocks = (D * D + 255) / 256;
        const int nGroups    = (gemmTiles + 1) / 2;
        const int permSlots  = nGroups * 3;
        const int mainBlocks = nGroups * 5;
        const int nScanBlocks = (n_nodes + SCAN_BLK - 1) / SCAN_BLK;

        hipMemsetAsync(counts, 0, (size_t)n_nodes * 4, stream);
        fused_pre<<<histBlocks + convBlocks, 256, 0, stream>>>(
            rows, counts, n_edges, W, Wb, histBlocks);
        scan_local<<<nScanBlocks, SCAN_BLK, 0, stream>>>(counts, offs, bsums, n_nodes);
        scan_blocks<<<1, 1024, 0, stream>>>(bsums, &offs[n_nodes], nScanBlocks);
        scan_add<<<nScanBlocks, SCAN_BLK, 0, stream>>>(offs, cursor, bsums, n_nodes);
        fused_main<<<mainBlocks, 256, 0, stream>>>(
            rows, cols, vals, cursor, evec, n_edges, permSlots,
            x, Wb, b, hb, n_nodes);
        aggregate<<<(n_nodes + 3) / 4, 256, 0, stream>>>(offs, evec, hb, out, n_nodes);
    }
}

// Round 15
// 141.592 us; speedup vs baseline: 2.8204x; 2.8204x over previous
//
#include <hip/hip_runtime.h>

#define D 128
#define SCAN_BLK 256
#define SCAN_THREADS 1024

typedef short  bf16x8 __attribute__((ext_vector_type(8)));
typedef float  f32x4  __attribute__((ext_vector_type(4)));

// round-to-nearest-even float -> bf16 bits
static __device__ __forceinline__ unsigned short f2bf(float f) {
    unsigned u = __float_as_uint(f);
    u += 0x7FFFu + ((u >> 16) & 1u);
    return (unsigned short)(u >> 16);
}
static __device__ __forceinline__ float bf2f_lo(unsigned u) {
    return __uint_as_float((u & 0xFFFFu) << 16);
}
static __device__ __forceinline__ float bf2f_hi(unsigned u) {
    return __uint_as_float(u & 0xFFFF0000u);
}

// ------------------------------------------------ fused: hist_rows + convert_W
__global__ __launch_bounds__(256) void fused_pre(
    const int* __restrict__ rows, int* __restrict__ counts, int n_edges,
    const float* __restrict__ W, unsigned short* __restrict__ Wb, int histBlocks) {
    int bid = blockIdx.x;
    if (bid < histBlocks) {
        int i = bid * 256 + threadIdx.x;
        if (i < n_edges) atomicAdd(&counts[rows[i]], 1);
    } else {
        int i = (bid - histBlocks) * 256 + threadIdx.x;
        if (i < D * D) Wb[i] = f2bf(W[i]);
    }
}

// ------------------------------------------------ fused: permute + MFMA GEMM
// R8/R11-proven: groups of 5 blocks = 2 gemm + 3 grid-stride permute slots,
// co-resident for the whole kernel. 8B {col,val} records.
__global__ __launch_bounds__(256) void fused_main(
    const int* __restrict__ rows, const int* __restrict__ cols,
    const float* __restrict__ vals, int* __restrict__ cursor,
    int2* __restrict__ evec, int n_edges, int permSlots,
    const float* __restrict__ x, const unsigned short* __restrict__ Wb,
    const float* __restrict__ b, unsigned short* __restrict__ hb, int n_rows) {
    const int bid = blockIdx.x;
    const int g   = bid / 5;
    const int r5  = bid % 5;

    if (r5 >= 2) {
        const int slot   = g * 3 + (r5 - 2);
        const int stride = permSlots * 256;
        for (int i = slot * 256 + threadIdx.x; i < n_edges; i += stride) {
            int rr  = rows[i];
            int pos = atomicAdd(&cursor[rr], 1);
            evec[pos] = make_int2(cols[i], __float_as_int(vals[i]));
        }
        return;
    }

    // ---- gemm slot: h[m][o] = sum_k x[m][k]*W[o][k] + b[o] -> bf16
    const int gb   = g * 2 + r5;
    const int lane = threadIdx.x & 63;
    const int wv   = threadIdx.x >> 6;
    const int row0 = gb * 64 + wv * 16;
    if (row0 >= n_rows) return;               // no __syncthreads in this path
    const int m  = lane & 15;
    const int kg = lane >> 4;                 // 0..3

    int arow = row0 + m;
    if (arow >= n_rows) arow = n_rows - 1;    // clamp: loads valid, stores predicated
    const float* xr = x + (size_t)arow * D + kg * 8;

    f32x4 acc[8];
#pragma unroll
    for (int n = 0; n < 8; ++n) acc[n] = (f32x4){0.f, 0.f, 0.f, 0.f};

#pragma unroll
    for (int ks = 0; ks < 4; ++ks) {
        float4 f0 = *(const float4*)(xr + ks * 32);
        float4 f1 = *(const float4*)(xr + ks * 32 + 4);
        bf16x8 a;
        a[0] = (short)f2bf(f0.x); a[1] = (short)f2bf(f0.y);
        a[2] = (short)f2bf(f0.z); a[3] = (short)f2bf(f0.w);
        a[4] = (short)f2bf(f1.x); a[5] = (short)f2bf(f1.y);
        a[6] = (short)f2bf(f1.z); a[7] = (short)f2bf(f1.w);
#pragma unroll
        for (int n = 0; n < 8; ++n) {
            bf16x8 bf = *(const bf16x8*)&Wb[(size_t)(n * 16 + m) * D + ks * 32 + kg * 8];
            acc[n] = __builtin_amdgcn_mfma_f32_16x16x32_bf16(a, bf, acc[n], 0, 0, 0);
        }
    }

#pragma unroll
    for (int n = 0; n < 8; ++n) {
        int col = n * 16 + m;
        float bc = b[col];
#pragma unroll
        for (int j = 0; j < 4; ++j) {
            int rr = row0 + kg * 4 + j;
            if (rr < n_rows) hb[(size_t)rr * D + col] = f2bf(acc[n][j] + bc);
        }
    }
}

// ---------------------------------------------------------------- scan chain
__global__ __launch_bounds__(SCAN_BLK) void scan_local(
    const int* __restrict__ counts, int* __restrict__ offs,
    int* __restrict__ blockSums, int n) {
    __shared__ int sh[SCAN_BLK];
    const int t = threadIdx.x;
    const int i = blockIdx.x * SCAN_BLK + t;
    int v = (i < n) ? counts[i] : 0;
    sh[t] = v;
    __syncthreads();
    for (int off = 1; off < SCAN_BLK; off <<= 1) {
        int add = (t >= off) ? sh[t - off] : 0;
        __syncthreads();
        sh[t] += add;
        __syncthreads();
    }
    if (i < n) offs[i] = sh[t] - v;
    if (t == SCAN_BLK - 1) blockSums[blockIdx.x] = sh[SCAN_BLK - 1];
}

__global__ __launch_bounds__(1024) void scan_blocks(
    int* __restrict__ blockSums, int* __restrict__ total, int nb) {
    __shared__ int sh[1024];
    const int t = threadIdx.x;
    int v = (t < nb) ? blockSums[t] : 0;
    sh[t] = v;
    __syncthreads();
    for (int off = 1; off < 1024; off <<= 1) {
        int add = (t >= off) ? sh[t - off] : 0;
        __syncthreads();
        sh[t] += add;
        __syncthreads();
    }
    if (t < nb) blockSums[t] = sh[t] - v;
    if (t == 1023) *total = sh[1023];
}

__global__ __launch_bounds__(SCAN_BLK) void scan_add(
    int* __restrict__ offs, int* __restrict__ cursor,
    const int* __restrict__ blockSums, int n) {
    const int i = blockIdx.x * SCAN_BLK + threadIdx.x;
    if (i < n) {
        int o = offs[i] + blockSums[blockIdx.x];
        offs[i]   = o;
        cursor[i] = o;
    }
}

__global__ __launch_bounds__(SCAN_THREADS) void scan_counts(
    const int* __restrict__ counts, int* __restrict__ offs,
    int* __restrict__ cursor, int n) {
    __shared__ int part[SCAN_THREADS];
    const int t = threadIdx.x;
    const int chunk = (n + SCAN_THREADS - 1) / SCAN_THREADS;
    const int s = t * chunk;
    const int e = min(s + chunk, n);
    int sum = 0;
    for (int i = s; i < e; ++i) sum += counts[i];
    part[t] = sum;
    __syncthreads();
    for (int off = 1; off < SCAN_THREADS; off <<= 1) {
        int add = (t >= off) ? part[t - off] : 0;
        __syncthreads();
        part[t] += add;
        __syncthreads();
    }
    int run = part[t] - sum;
    for (int i = s; i < e; ++i) {
        offs[i]   = run;
        cursor[i] = run;
        run += counts[i];
    }
    if (e == n) offs[n] = run;
}

// ---------------------------------------------------------------- aggregate
// One wave per node; lane owns 2 cols (4 B of bf16 h per gather).
// 8 records in flight per iteration (4x int4 broadcast evec loads + 8 gathers).
__global__ __launch_bounds__(256, 4) void aggregate(
    const int* __restrict__ offs, const int2* __restrict__ evec,
    const unsigned short* __restrict__ hb, float* __restrict__ out, int n_nodes) {
    int wid = blockIdx.x * 4 + (threadIdx.x >> 6);
    if (wid >= n_nodes) return;
    int lane = threadIdx.x & 63;

    int s = offs[wid];
    int e = offs[wid + 1];
    const int c0 = lane * 2;
    float2 acc = make_float2(0.f, 0.f);

    int k = s;
    if ((k & 1) && k < e) {   // peel to even k -> 16B-aligned int4 loads
        int2 e0 = evec[k];
        unsigned u0 = *(const unsigned*)&hb[(size_t)e0.x * D + c0];
        float v0 = __int_as_float(e0.y);
        acc.x += v0 * bf2f_lo(u0); acc.y += v0 * bf2f_hi(u0);
        ++k;
    }
    for (; k + 7 < e; k += 8) {
        int4 p0 = *(const int4*)&evec[k];
        int4 p1 = *(const int4*)&evec[k + 2];
        int4 p2 = *(const int4*)&evec[k + 4];
        int4 p3 = *(const int4*)&evec[k + 6];
        unsigned u0 = *(const unsigned*)&hb[(size_t)p0.x * D + c0];
        unsigned u1 = *(const unsigned*)&hb[(size_t)p0.z * D + c0];
        unsigned u2 = *(const unsigned*)&hb[(size_t)p1.x * D + c0];
        unsigned u3 = *(const unsigned*)&hb[(size_t)p1.z * D + c0];
        unsigned u4 = *(const unsigned*)&hb[(size_t)p2.x * D + c0];
        unsigned u5 = *(const unsigned*)&hb[(size_t)p2.z * D + c0];
        unsigned u6 = *(const unsigned*)&hb[(size_t)p3.x * D + c0];
        unsigned u7 = *(const unsigned*)&hb[(size_t)p3.z * D + c0];
        float v0 = __int_as_float(p0.y), v1 = __int_as_float(p0.w);
        float v2 = __int_as_float(p1.y), v3 = __int_as_float(p1.w);
        float v4 = __int_as_float(p2.y), v5 = __int_as_float(p2.w);
        float v6 = __int_as_float(p3.y), v7 = __int_as_float(p3.w);
        acc.x += v0 * bf2f_lo(u0); acc.y += v0 * bf2f_hi(u0);
        acc.x += v1 * bf2f_lo(u1); acc.y += v1 * bf2f_hi(u1);
        acc.x += v2 * bf2f_lo(u2); acc.y += v2 * bf2f_hi(u2);
        acc.x += v3 * bf2f_lo(u3); acc.y += v3 * bf2f_hi(u3);
        acc.x += v4 * bf2f_lo(u4); acc.y += v4 * bf2f_hi(u4);
        acc.x += v5 * bf2f_lo(u5); acc.y += v5 * bf2f_hi(u5);
        acc.x += v6 * bf2f_lo(u6); acc.y += v6 * bf2f_hi(u6);
        acc.x += v7 * bf2f_lo(u7); acc.y += v7 * bf2f_hi(u7);
    }
    for (; k + 1 < e; k += 2) {
        int4 p0 = *(const int4*)&evec[k];
        unsigned u0 = *(const unsigned*)&hb[(size_t)p0.x * D + c0];
        unsigned u1 = *(const unsigned*)&hb[(size_t)p0.z * D + c0];
        float v0 = __int_as_float(p0.y), v1 = __int_as_float(p0.w);
        acc.x += v0 * bf2f_lo(u0); acc.y += v0 * bf2f_hi(u0);
        acc.x += v1 * bf2f_lo(u1); acc.y += v1 * bf2f_hi(u1);
    }
    if (k < e) {
        int2 e0 = evec[k];
        unsigned u0 = *(const unsigned*)&hb[(size_t)e0.x * D + c0];
        float v0 = __int_as_float(e0.y);
        acc.x += v0 * bf2f_lo(u0); acc.y += v0 * bf2f_hi(u0);
    }

    *(float2*)&out[(size_t)wid * D + c0] = acc;
}

// ---------------------------------------------------------------- fallback
__global__ __launch_bounds__(256) void scatter_add(
    const int* __restrict__ rows, const int* __restrict__ cols,
    const float* __restrict__ vals, const unsigned short* __restrict__ hb,
    float* __restrict__ out, int n_edges) {
    long long gid = (long long)blockIdx.x * blockDim.x + threadIdx.x;
    int e  = (int)(gid >> 5);
    if (e >= n_edges) return;
    int d4 = ((int)gid & 31) * 4;
    int   r = rows[e];
    int   c = cols[e];
    float v = vals[e];
    const unsigned short* hp = &hb[(size_t)c * D + d4];
    unsigned u0 = *(const unsigned*)(hp + 0);
    unsigned u1 = *(const unsigned*)(hp + 2);
    float* op = &out[(size_t)r * D + d4];
    atomicAdd(op + 0, v * bf2f_lo(u0));
    atomicAdd(op + 1, v * bf2f_hi(u0));
    atomicAdd(op + 2, v * bf2f_lo(u1));
    atomicAdd(op + 3, v * bf2f_hi(u1));
}

__global__ void convert_W(const float* __restrict__ W, unsigned short* __restrict__ Wb) {
    int i = blockIdx.x * blockDim.x + threadIdx.x;
    if (i < D * D) Wb[i] = f2bf(W[i]);
}

__global__ __launch_bounds__(256) void gemm_mfma(
    const float* __restrict__ x, const unsigned short* __restrict__ Wb,
    const float* __restrict__ b, unsigned short* __restrict__ hb, int n_rows) {
    const int lane = threadIdx.x & 63;
    const int wv   = threadIdx.x >> 6;
    const int row0 = blockIdx.x * 64 + wv * 16;
    if (row0 >= n_rows) return;
    const int m  = lane & 15;
    const int kg = lane >> 4;
    int arow = row0 + m;
    if (arow >= n_rows) arow = n_rows - 1;
    const float* xr = x + (size_t)arow * D + kg * 8;
    f32x4 acc[8];
#pragma unroll
    for (int n = 0; n < 8; ++n) acc[n] = (f32x4){0.f, 0.f, 0.f, 0.f};
#pragma unroll
    for (int ks = 0; ks < 4; ++ks) {
        float4 f0 = *(const float4*)(xr + ks * 32);
        float4 f1 = *(const float4*)(xr + ks * 32 + 4);
        bf16x8 a;
        a[0] = (short)f2bf(f0.x); a[1] = (short)f2bf(f0.y);
        a[2] = (short)f2bf(f0.z); a[3] = (short)f2bf(f0.w);
        a[4] = (short)f2bf(f1.x); a[5] = (short)f2bf(f1.y);
        a[6] = (short)f2bf(f1.z); a[7] = (short)f2bf(f1.w);
#pragma unroll
        for (int n = 0; n < 8; ++n) {
            bf16x8 bf = *(const bf16x8*)&Wb[(size_t)(n * 16 + m) * D + ks * 32 + kg * 8];
            acc[n] = __builtin_amdgcn_mfma_f32_16x16x32_bf16(a, bf, acc[n], 0, 0, 0);
        }
    }
#pragma unroll
    for (int n = 0; n < 8; ++n) {
        int col = n * 16 + m;
        float bc = b[col];
#pragma unroll
        for (int j = 0; j < 4; ++j) {
            int r = row0 + kg * 4 + j;
            if (r < n_rows) hb[(size_t)r * D + col] = f2bf(acc[n][j] + bc);
        }
    }
}

// ---------------------------------------------------------------- launch
static inline size_t align16(size_t x) { return (x + 15) & ~(size_t)15; }

extern "C" void kernel_launch(void* const* d_in, const int* in_sizes, int n_in,
                              void* d_out, int out_size, void* d_ws, size_t ws_size,
                              hipStream_t stream) {
    const float* x    = (const float*)d_in[0];
    const int*   rows = (const int*)  d_in[1];
    const int*   cols = (const int*)  d_in[2];
    const float* vals = (const float*)d_in[3];
    const float* W    = (const float*)d_in[4];
    const float* b    = (const float*)d_in[5];
    float*       out  = (float*)d_out;

    const int n_nodes = in_sizes[0] / D;   // 50000
    const int n_edges = in_sizes[1];       // 800000
    const int nScanBlocks = (n_nodes + SCAN_BLK - 1) / SCAN_BLK;
    const int histBlocks  = (n_edges + 255) / 256;
    const int convBlocks  = (D * D + 255) / 256;
    const int gemmBlocks  = (n_nodes + 63) / 64;           // 782
    const int nGroups     = (gemmBlocks + 1) / 2;          // 391
    const int permSlots   = nGroups * 3;                   // 1173
    const int mainBlocks  = nGroups * 5;

    // ---- workspace layout (16B-aligned regions)
    char*  base    = (char*)d_ws;
    size_t off     = 0;
    unsigned short* Wb = (unsigned short*)(base + off); off = align16(off + (size_t)D * D * 2);
    unsigned short* hb = (unsigned short*)(base + off); off = align16(off + (size_t)n_nodes * D * 2);
    int*   counts  = (int*)  (base + off); off = align16(off + (size_t)n_nodes * 4);
    int*   offs    = (int*)  (base + off); off = align16(off + ((size_t)n_nodes + 1) * 4);
    int*   cursor  = (int*)  (base + off); off = align16(off + (size_t)n_nodes * 4);
    int*   bsums   = (int*)  (base + off); off = align16(off + (size_t)1024 * 4);
    int2*  evec    = (int2*) (base + off); off = align16(off + (size_t)n_edges * 8);
    const bool csr_fits = (off <= ws_size);

    if (csr_fits) {
        hipMemsetAsync(counts, 0, (size_t)n_nodes * 4, stream);
        fused_pre<<<histBlocks + convBlocks, 256, 0, stream>>>(
            rows, counts, n_edges, W, Wb, histBlocks);
        if (nScanBlocks <= 1024) {
            scan_local<<<nScanBlocks, SCAN_BLK, 0, stream>>>(counts, offs, bsums, n_nodes);
            scan_blocks<<<1, 1024, 0, stream>>>(bsums, &offs[n_nodes], nScanBlocks);
            scan_add<<<nScanBlocks, SCAN_BLK, 0, stream>>>(offs, cursor, bsums, n_nodes);
        } else {
            scan_counts<<<1, SCAN_THREADS, 0, stream>>>(counts, offs, cursor, n_nodes);
        }
        fused_main<<<mainBlocks, 256, 0, stream>>>(
            rows, cols, vals, cursor, evec, n_edges, permSlots,
            x, Wb, b, hb, n_nodes);
        aggregate<<<(n_nodes + 3) / 4, 256, 0, stream>>>(offs, evec, hb, out, n_nodes);
    } else {
        convert_W<<<convBlocks, 256, 0, stream>>>(W, Wb);
        gemm_mfma<<<gemmBlocks, 256, 0, stream>>>(x, Wb, b, hb, n_nodes);
        hipMemsetAsync(d_out, 0, (size_t)n_nodes * D * sizeof(float), stream);
        long long scatter_threads = (long long)n_edges * 32;
        int scatter_blocks = (int)((scatter_threads + 255) / 256);
        scatter_add<<<scatter_blocks, 256, 0, stream>>>(rows, cols, vals, hb, out, n_edges);
    }
}